// Round 1
// baseline (994.082 us; speedup 1.0000x reference)
//
#include <hip/hip_runtime.h>
#include <hip/hip_bf16.h>

typedef __bf16 bf16_t;
typedef bf16_t bf16x8 __attribute__((ext_vector_type(8)));
typedef bf16_t bf16x4 __attribute__((ext_vector_type(4)));
typedef bf16_t bf16x2 __attribute__((ext_vector_type(2)));
typedef float  f32x4  __attribute__((ext_vector_type(4)));

#define EPS 1e-5f

// ---------------------------------------------------------------------------
// Prep: BN scale folded into W1 rows (k-dim), BN shift folded into b1.
// Weight transpose/convert into MFMA fragment layout:
// frag[(kt*NT + nt)*64 + lane][j] = W[nt*16 + (lane&15)][kt*32 + (lane>>4)*8 + j]
// ---------------------------------------------------------------------------
__global__ __launch_bounds__(256) void prep_kernel(
    const float* __restrict__ op_w1, const float* __restrict__ op_w2,
    const float* __restrict__ nm_w1, const float* __restrict__ nm_w2,
    const float* __restrict__ op_g, const float* __restrict__ op_b,
    const float* __restrict__ op_m, const float* __restrict__ op_v,
    const float* __restrict__ nm_g, const float* __restrict__ nm_b,
    const float* __restrict__ nm_m, const float* __restrict__ nm_v,
    const float* __restrict__ op_b1, const float* __restrict__ nm_b1,
    bf16_t* __restrict__ w1f, bf16_t* __restrict__ w2f,
    bf16_t* __restrict__ nw1f, bf16_t* __restrict__ nw2f,
    float* __restrict__ b1p, float* __restrict__ b1n)
{
    int t = blockIdx.x * 256 + threadIdx.x;
    if (t < 4096) {                       // op_w1: [256 out][128 in] -> [kt<4][nt<16][64][8], BN-scaled
        int g = t, lane = g & 63, nt = (g >> 6) & 15, kt = g >> 10;
        int n = nt * 16 + (lane & 15);
        int k0 = kt * 32 + (lane >> 4) * 8;
        const float* src = op_w1 + (size_t)n * 128 + k0;
        bf16x8 v;
        for (int j = 0; j < 8; ++j) {
            int i = k0 + j;
            float s = op_g[i] * rsqrtf(op_v[i] + EPS);
            v[j] = (bf16_t)(src[j] * s);
        }
        *(bf16x8*)(w1f + (size_t)g * 8) = v;
    } else if (t < 12288) {               // op_w2: [256][256] -> [kt<8][nt<16][64][8]
        int g = t - 4096, lane = g & 63, nt = (g >> 6) & 15, kt = g >> 10;
        int n = nt * 16 + (lane & 15);
        int k0 = kt * 32 + (lane >> 4) * 8;
        const float* src = op_w2 + (size_t)n * 256 + k0;
        bf16x8 v;
        for (int j = 0; j < 8; ++j) v[j] = (bf16_t)src[j];
        *(bf16x8*)(w2f + (size_t)g * 8) = v;
    } else if (t < 14336) {               // nm_w1: [128][128] -> [kt<4][nt<8][64][8], BN-scaled
        int g = t - 12288, lane = g & 63, nt = (g >> 6) & 7, kt = g >> 9;
        int n = nt * 16 + (lane & 15);
        int k0 = kt * 32 + (lane >> 4) * 8;
        const float* src = nm_w1 + (size_t)n * 128 + k0;
        bf16x8 v;
        for (int j = 0; j < 8; ++j) {
            int i = k0 + j;
            float s = nm_g[i] * rsqrtf(nm_v[i] + EPS);
            v[j] = (bf16_t)(src[j] * s);
        }
        *(bf16x8*)(nw1f + (size_t)g * 8) = v;
    } else if (t < 16384) {               // nm_w2: [128][128] -> [kt<4][nt<8][64][8]
        int g = t - 14336, lane = g & 63, nt = (g >> 6) & 7, kt = g >> 9;
        int n = nt * 16 + (lane & 15);
        int k0 = kt * 32 + (lane >> 4) * 8;
        const float* src = nm_w2 + (size_t)n * 128 + k0;
        bf16x8 v;
        for (int j = 0; j < 8; ++j) v[j] = (bf16_t)src[j];
        *(bf16x8*)(nw2f + (size_t)g * 8) = v;
    } else if (t < 16640) {               // b1p[o] = op_b1[o] + op_w1[o,:] @ shift
        int o = t - 16384;
        float acc = op_b1[o];
        const float* wrow = op_w1 + (size_t)o * 128;
        for (int i = 0; i < 128; ++i) {
            float s  = op_g[i] * rsqrtf(op_v[i] + EPS);
            float sh = op_b[i] - op_m[i] * s;
            acc += wrow[i] * sh;
        }
        b1p[o] = acc;
    } else if (t < 16768) {               // b1n[o] = nm_b1[o] + nm_w1[o,:] @ shift
        int o = t - 16640;
        float acc = nm_b1[o];
        const float* wrow = nm_w1 + (size_t)o * 128;
        for (int i = 0; i < 128; ++i) {
            float s  = nm_g[i] * rsqrtf(nm_v[i] + EPS);
            float sh = nm_b[i] - nm_m[i] * s;
            acc += wrow[i] * sh;
        }
        b1n[o] = acc;
    }
}

// ---------------------------------------------------------------------------
// Kernel 1: Linear(128->256,BN-folded) + ReLU + Linear(256->256) -> y (bf16)
// 64 tokens / block, 4 waves. GEMM1 computes with SWAPPED operands
// (mfma(W_frag, X_frag)) so each lane holds 4 consecutive out-channels for
// one token -> Hf write is a single ds_write_b64 per (nt,m).
// Ax (16 KB) is aliased into Hf (32 KB): total LDS 32 KB -> 4+ blocks/CU.
// Also fuses the CSR count pass (128 tix entries / block).
// ---------------------------------------------------------------------------
__global__ __launch_bounds__(256, 4) void mlp1_y(
    const float* __restrict__ x,
    const int* __restrict__ tix, int* __restrict__ cnt,
    const bf16_t* __restrict__ w1f, const bf16_t* __restrict__ w2f,
    const float* __restrict__ b1, const float* __restrict__ b2,
    bf16_t* __restrict__ y, int T, int T2)
{
    __shared__ __align__(16) bf16_t S[4 * 8 * 64 * 8];   // 32 KB; Ax(16K) aliased under Hf(32K)
    const int tid  = threadIdx.x;
    const int base = blockIdx.x * 64;

    // ---- fused CSR count: 128 entries per block ----
    if (tid < 128) {
        int e = blockIdx.x * 128 + tid;
        if (e < T2) atomicAdd(&cnt[tix[e]], 1);
    }

    // ---- stage X tile (BN already folded into weights) into B-frag layout ----
    {
        const int rr = tid >> 4;      // 0..15
        const int kg = tid & 15;      // 8-col group
        const int c0 = kg * 8;
        for (int p = 0; p < 4; ++p) {
            int r   = p * 16 + rr;
            int tok = base + r;
            float f[8];
            if (tok < T) {
                const float4* xp = (const float4*)(x + (size_t)tok * 128 + c0);
                float4 u = xp[0], w = xp[1];
                f[0] = u.x; f[1] = u.y; f[2] = u.z; f[3] = u.w;
                f[4] = w.x; f[5] = w.y; f[6] = w.z; f[7] = w.w;
            } else {
                for (int j = 0; j < 8; ++j) f[j] = 0.f;
            }
            bf16x8 v;
            for (int j = 0; j < 8; ++j) v[j] = (bf16_t)f[j];
            int flat = ((p * 4 + (kg >> 2)) * 64 + (kg & 3) * 16 + rr) * 8;
            *(bf16x8*)(S + flat) = v;
        }
    }
    __syncthreads();

    const int w     = tid >> 6;       // wave id = nt residue
    const int l     = tid & 63;
    const int colL  = l & 15;
    const int quadw = l >> 4;

    // ---- pull entire X tile into registers, then free the Ax region ----
    bf16x8 a1[16];                    // [m][kt]
    for (int m = 0; m < 4; ++m)
        for (int kt = 0; kt < 4; ++kt)
            a1[m * 4 + kt] = *(const bf16x8*)(S + ((m * 4 + kt) * 64 + l) * 8);
    __syncthreads();                  // all Ax reads done before Hf overwrites

    // ---- GEMM1 (swapped): C rows = channels, cols = tokens ----
    for (int nt_l = 0; nt_l < 4; ++nt_l) {
        const int nt = nt_l * 4 + w;
        f32x4 acc[4];
        for (int m = 0; m < 4; ++m) acc[m] = (f32x4){0.f, 0.f, 0.f, 0.f};
        for (int kt = 0; kt < 4; ++kt) {
            bf16x8 b = *(const bf16x8*)(w1f + (size_t)((kt * 16 + nt) * 64 + l) * 8);
            for (int m = 0; m < 4; ++m)
                acc[m] = __builtin_amdgcn_mfma_f32_16x16x32_bf16(b, a1[m * 4 + kt], acc[m], 0, 0, 0);
        }
        f32x4 bv = *(const f32x4*)(b1 + nt * 16 + 4 * quadw);
        const int kt2 = nt >> 1;
        const int lp  = ((2 * nt + (quadw >> 1)) & 3) * 16 + colL;
        const int jb  = 4 * (quadw & 1);
        for (int m = 0; m < 4; ++m) {
            bf16x4 hv;
            for (int reg = 0; reg < 4; ++reg) {
                float h = acc[m][reg] + bv[reg];
                hv[reg] = (bf16_t)(h > 0.f ? h : 0.f);
            }
            *(bf16x4*)(S + ((m * 8 + kt2) * 64 + lp) * 8 + jb) = hv;
        }
    }
    __syncthreads();

    // ---- GEMM2 (unswapped): Y = H * W2^T + b2; wave w does nt%4==w ----
    for (int mp = 0; mp < 2; ++mp) {
        bf16x8 a2[16];                 // [mm<2][kt<8]
        for (int mm = 0; mm < 2; ++mm)
            for (int kt = 0; kt < 8; ++kt)
                a2[mm * 8 + kt] = *(const bf16x8*)(S + (((2 * mp + mm) * 8 + kt) * 64 + l) * 8);
        for (int nt_l = 0; nt_l < 4; ++nt_l) {
            const int nt = nt_l * 4 + w;
            f32x4 acc0 = {0.f, 0.f, 0.f, 0.f};
            f32x4 acc1 = {0.f, 0.f, 0.f, 0.f};
            for (int kt = 0; kt < 8; ++kt) {
                bf16x8 b = *(const bf16x8*)(w2f + (size_t)((kt * 16 + nt) * 64 + l) * 8);
                acc0 = __builtin_amdgcn_mfma_f32_16x16x32_bf16(a2[kt],     b, acc0, 0, 0, 0);
                acc1 = __builtin_amdgcn_mfma_f32_16x16x32_bf16(a2[8 + kt], b, acc1, 0, 0, 0);
            }
            float bb = b2[nt * 16 + colL];
            int c = nt * 16 + colL;
            for (int reg = 0; reg < 4; ++reg) {
                int r0 = base + (2 * mp) * 16 + quadw * 4 + reg;
                int r1 = base + (2 * mp + 1) * 16 + quadw * 4 + reg;
                if (r0 < T) y[(size_t)r0 * 256 + c] = (bf16_t)(acc0[reg] + bb);
                if (r1 < T) y[(size_t)r1 * 256 + c] = (bf16_t)(acc1[reg] + bb);
            }
        }
    }
}

// ---------------------------------------------------------------------------
// CSR build: scan (3 kernels) -> fill   (count is fused into mlp1_y)
// ---------------------------------------------------------------------------
__global__ __launch_bounds__(256) void scan1(
    const int* __restrict__ cnt, int* __restrict__ bsum, int N)
{
    __shared__ int lds[256];
    int t = threadIdx.x;
    int i0 = blockIdx.x * 1024 + t * 4;
    int s = 0;
    for (int j = 0; j < 4; ++j) { int i = i0 + j; s += (i < N) ? cnt[i] : 0; }
    lds[t] = s; __syncthreads();
    for (int off = 1; off < 256; off <<= 1) {
        int v = (t >= off) ? lds[t - off] : 0;
        __syncthreads(); lds[t] += v; __syncthreads();
    }
    if (t == 255) bsum[blockIdx.x] = lds[255];
}

__global__ __launch_bounds__(256) void scan2(
    const int* __restrict__ bsum, int* __restrict__ bpref, int nb)
{
    __shared__ int lds[256];
    int t = threadIdx.x;
    int s = (t < nb) ? bsum[t] : 0;
    lds[t] = s; __syncthreads();
    for (int off = 1; off < 256; off <<= 1) {
        int v = (t >= off) ? lds[t - off] : 0;
        __syncthreads(); lds[t] += v; __syncthreads();
    }
    if (t < nb) bpref[t] = lds[t] - s;   // exclusive
}

__global__ __launch_bounds__(256) void scan3(
    const int* __restrict__ cnt, const int* __restrict__ bpref,
    int* __restrict__ offs, int* __restrict__ run, int N)
{
    __shared__ int lds[256];
    int t = threadIdx.x;
    int i0 = blockIdx.x * 1024 + t * 4;
    int c[4]; int s = 0;
    for (int j = 0; j < 4; ++j) { int i = i0 + j; c[j] = (i < N) ? cnt[i] : 0; s += c[j]; }
    lds[t] = s; __syncthreads();
    for (int off = 1; off < 256; off <<= 1) {
        int v = (t >= off) ? lds[t - off] : 0;
        __syncthreads(); lds[t] += v; __syncthreads();
    }
    int p = lds[t] - s + bpref[blockIdx.x];
    for (int j = 0; j < 4; ++j) {
        int i = i0 + j;
        if (i < N) { offs[i] = p; run[i] = p; }
        p += c[j];
    }
}

__global__ __launch_bounds__(256) void fill_kernel(
    const int* __restrict__ tix, int* __restrict__ run,
    int* __restrict__ entries, int T2, int T)
{
    int i = blockIdx.x * 256 + threadIdx.x;
    if (i < T2) {
        int n = tix[i];
        int s = (i >= T) ? 1 : 0;
        int t = s ? (i - T) : i;
        int pos = atomicAdd(&run[n], 1);
        entries[pos] = (t << 1) | s;   // y offset of entry = ent*128
    }
}

// ---------------------------------------------------------------------------
// Kernel 2: gather (segment-sum of y) + node MLP fused, writes d_out.
// 64 nodes / block. LDS is fully wave-private (each wave owns one 4 KB
// quarter for staging, GEMM1 H, and GEMM2 input) -> single 16 KB aliased
// buffer, NO barriers: waves with unequal gather loads never sync.
// GEMM1 swapped-operand like mlp1_y -> vector b64 H writes.
// ---------------------------------------------------------------------------
__global__ __launch_bounds__(256, 4) void gather_mlp2(
    const bf16_t* __restrict__ y,
    const int* __restrict__ offs, const int* __restrict__ cnt,
    const int* __restrict__ entries,
    const bf16_t* __restrict__ w1f, const bf16_t* __restrict__ w2f,
    const float* __restrict__ b1, const float* __restrict__ b2,
    float* __restrict__ out, int N)
{
    __shared__ __align__(16) bf16_t S[4 * 4 * 64 * 8];   // 16 KB, wave-private quarters
    const int tid  = threadIdx.x;
    const int base = blockIdx.x * 64;
    const int w    = tid >> 6;
    const int l    = tid & 63;

    // ---- gather (BN folded into weights), write B-frags into own quarter ----
    {
        const int half = l >> 5;          // which of 2 concurrent nodes
        const int cl   = l & 31;
        const int c0   = cl * 4;          // 4 columns per lane
        for (int ii = 0; ii < 8; ++ii) {
            int r = w * 16 + ii * 2 + half;
            int n = base + r;
            float a[4] = {0.f, 0.f, 0.f, 0.f};
            if (n < N) {
                int e0 = offs[n], c = cnt[n];
                int e = 0;
                for (; e + 4 <= c; e += 4) {
                    int t0 = entries[e0 + e];
                    int t1 = entries[e0 + e + 1];
                    int t2 = entries[e0 + e + 2];
                    int t3 = entries[e0 + e + 3];
                    bf16x4 v0 = *(const bf16x4*)(y + (size_t)t0 * 128 + c0);
                    bf16x4 v1 = *(const bf16x4*)(y + (size_t)t1 * 128 + c0);
                    bf16x4 v2 = *(const bf16x4*)(y + (size_t)t2 * 128 + c0);
                    bf16x4 v3 = *(const bf16x4*)(y + (size_t)t3 * 128 + c0);
                    for (int j = 0; j < 4; ++j)
                        a[j] += ((float)v0[j] + (float)v1[j]) + ((float)v2[j] + (float)v3[j]);
                }
                for (; e < c; ++e) {
                    int t0 = entries[e0 + e];
                    bf16x4 v0 = *(const bf16x4*)(y + (size_t)t0 * 128 + c0);
                    for (int j = 0; j < 4; ++j) a[j] += (float)v0[j];
                }
            }
            bf16x4 pv;
            for (int j = 0; j < 4; ++j) pv[j] = (bf16_t)a[j];
            int idx = ((w * 4 + (c0 >> 5)) * 64 + ((c0 >> 3) & 3) * 16 + (r & 15)) * 8 + (c0 & 7);
            *(bf16x4*)(S + idx) = pv;
        }
    }
    // no barrier: all LDS traffic below stays inside this wave's quarter

    const int mt    = w;
    const int colL  = l & 15;
    const int quadw = l >> 4;

    bf16x8 a1f[4];
    for (int kt = 0; kt < 4; ++kt)
        a1f[kt] = *(const bf16x8*)(S + ((mt * 4 + kt) * 64 + l) * 8);

    // ---- GEMM1 (swapped): lane holds 4 consecutive channels, 1 node ----
    for (int nt = 0; nt < 8; ++nt) {
        f32x4 acc = {0.f, 0.f, 0.f, 0.f};
        for (int kt = 0; kt < 4; ++kt) {
            bf16x8 b = *(const bf16x8*)(w1f + (size_t)((kt * 8 + nt) * 64 + l) * 8);
            acc = __builtin_amdgcn_mfma_f32_16x16x32_bf16(b, a1f[kt], acc, 0, 0, 0);
        }
        f32x4 bv = *(const f32x4*)(b1 + nt * 16 + 4 * quadw);
        const int kt2 = nt >> 1;
        const int lp  = ((2 * nt + (quadw >> 1)) & 3) * 16 + colL;
        const int jb  = 4 * (quadw & 1);
        bf16x4 hv;
        for (int reg = 0; reg < 4; ++reg) {
            float h = acc[reg] + bv[reg];
            hv[reg] = (bf16_t)(h > 0.f ? h : 0.f);
        }
        *(bf16x4*)(S + ((mt * 4 + kt2) * 64 + lp) * 8 + jb) = hv;
    }

    bf16x8 a2f[4];
    for (int kt = 0; kt < 4; ++kt)
        a2f[kt] = *(const bf16x8*)(S + ((mt * 4 + kt) * 64 + l) * 8);
    for (int nt = 0; nt < 8; ++nt) {
        f32x4 acc = {0.f, 0.f, 0.f, 0.f};
        for (int kt = 0; kt < 4; ++kt) {
            bf16x8 b = *(const bf16x8*)(w2f + (size_t)((kt * 8 + nt) * 64 + l) * 8);
            acc = __builtin_amdgcn_mfma_f32_16x16x32_bf16(a2f[kt], b, acc, 0, 0, 0);
        }
        float bb = b2[nt * 16 + colL];
        int c = nt * 16 + colL;
        for (int reg = 0; reg < 4; ++reg) {
            int row = base + mt * 16 + quadw * 4 + reg;
            if (row < N) out[(size_t)row * 128 + c] = acc[reg] + bb;
        }
    }
}

// ---------------------------------------------------------------------------
extern "C" void kernel_launch(void* const* d_in, const int* in_sizes, int n_in,
                              void* d_out, int out_size, void* d_ws, size_t ws_size,
                              hipStream_t stream)
{
    const float* x     = (const float*)d_in[0];
    const int*   tix   = (const int*)d_in[3];
    const float* op_g  = (const float*)d_in[4];
    const float* op_b  = (const float*)d_in[5];
    const float* op_m  = (const float*)d_in[6];
    const float* op_v  = (const float*)d_in[7];
    const float* op_w1 = (const float*)d_in[8];
    const float* op_b1 = (const float*)d_in[9];
    const float* op_w2 = (const float*)d_in[10];
    const float* op_b2 = (const float*)d_in[11];
    const float* nm_g  = (const float*)d_in[12];
    const float* nm_b  = (const float*)d_in[13];
    const float* nm_m  = (const float*)d_in[14];
    const float* nm_v  = (const float*)d_in[15];
    const float* nm_w1 = (const float*)d_in[16];
    const float* nm_b1 = (const float*)d_in[17];
    const float* nm_w2 = (const float*)d_in[18];
    const float* nm_b2 = (const float*)d_in[19];

    const int T  = in_sizes[0] / 128;
    const int N  = in_sizes[2];
    const int T2 = 2 * T;

    char* w = (char*)d_ws;
    size_t off = 0;
    bf16_t* y = (bf16_t*)w;              off += (size_t)T * 256 * 2;
    off = (off + 255) & ~(size_t)255;
    bf16_t* w1f  = (bf16_t*)(w + off);   off += (size_t)4096 * 8 * 2;
    bf16_t* w2f  = (bf16_t*)(w + off);   off += (size_t)8192 * 8 * 2;
    bf16_t* nw1f = (bf16_t*)(w + off);   off += (size_t)2048 * 8 * 2;
    bf16_t* nw2f = (bf16_t*)(w + off);   off += (size_t)2048 * 8 * 2;
    float* b1p   = (float*)(w + off);    off += 256 * 4;
    float* b1n   = (float*)(w + off);    off += 128 * 4;
    int* cnt     = (int*)(w + off);      off += (size_t)N * 4;
    int* offs    = (int*)(w + off);      off += (size_t)N * 4;
    int* run     = (int*)(w + off);      off += (size_t)N * 4;
    int* bsum    = (int*)(w + off);      off += 1024 * 4;
    int* bpref   = (int*)(w + off);      off += 1024 * 4;
    int* entries = (int*)(w + off);      off += (size_t)T2 * 4;

    const int nb = (N + 1023) / 1024;    // scan blocks (must be <= 256)

    hipMemsetAsync(cnt, 0, (size_t)N * 4, stream);
    prep_kernel<<<66, 256, 0, stream>>>(op_w1, op_w2, nm_w1, nm_w2,
                                        op_g, op_b, op_m, op_v,
                                        nm_g, nm_b, nm_m, nm_v,
                                        op_b1, nm_b1,
                                        w1f, w2f, nw1f, nw2f, b1p, b1n);
    mlp1_y<<<(T + 63) / 64, 256, 0, stream>>>(x, tix, cnt, w1f, w2f,
                                              b1p, op_b2, y, T, T2);
    scan1<<<nb, 256, 0, stream>>>(cnt, bsum, N);
    scan2<<<1, 256, 0, stream>>>(bsum, bpref, nb);
    scan3<<<nb, 256, 0, stream>>>(cnt, bpref, offs, run, N);
    fill_kernel<<<(T2 + 255) / 256, 256, 0, stream>>>(tix, run, entries, T2, T);
    gather_mlp2<<<(N + 63) / 64, 256, 0, stream>>>(y, offs, cnt, entries,
                                                   nw1f, nw2f,
                                                   b1n, nm_b2, (float*)d_out, N);
}

// Round 3
// 846.989 us; speedup vs baseline: 1.1737x; 1.1737x over previous
//
#include <hip/hip_runtime.h>
#include <hip/hip_bf16.h>

typedef __bf16 bf16_t;
typedef bf16_t bf16x8 __attribute__((ext_vector_type(8)));
typedef bf16_t bf16x4 __attribute__((ext_vector_type(4)));
typedef bf16_t bf16x2 __attribute__((ext_vector_type(2)));
typedef float  f32x4  __attribute__((ext_vector_type(4)));

#define EPS 1e-5f

// ---------------------------------------------------------------------------
// Prep: BN scale folded into W1 rows (k-dim), BN shift folded into b1.
// Weight transpose/convert into MFMA fragment layout:
// frag[(kt*NT + nt)*64 + lane][j] = W[nt*16 + (lane&15)][kt*32 + (lane>>4)*8 + j]
// ---------------------------------------------------------------------------
__global__ __launch_bounds__(256) void prep_kernel(
    const float* __restrict__ op_w1, const float* __restrict__ op_w2,
    const float* __restrict__ nm_w1, const float* __restrict__ nm_w2,
    const float* __restrict__ op_g, const float* __restrict__ op_b,
    const float* __restrict__ op_m, const float* __restrict__ op_v,
    const float* __restrict__ nm_g, const float* __restrict__ nm_b,
    const float* __restrict__ nm_m, const float* __restrict__ nm_v,
    const float* __restrict__ op_b1, const float* __restrict__ nm_b1,
    bf16_t* __restrict__ w1f, bf16_t* __restrict__ w2f,
    bf16_t* __restrict__ nw1f, bf16_t* __restrict__ nw2f,
    float* __restrict__ b1p, float* __restrict__ b1n)
{
    int t = blockIdx.x * 256 + threadIdx.x;
    if (t < 4096) {                       // op_w1: [256 out][128 in] -> [kt<4][nt<16][64][8], BN-scaled
        int g = t, lane = g & 63, nt = (g >> 6) & 15, kt = g >> 10;
        int n = nt * 16 + (lane & 15);
        int k0 = kt * 32 + (lane >> 4) * 8;
        const float* src = op_w1 + (size_t)n * 128 + k0;
        bf16x8 v;
        for (int j = 0; j < 8; ++j) {
            int i = k0 + j;
            float s = op_g[i] * rsqrtf(op_v[i] + EPS);
            v[j] = (bf16_t)(src[j] * s);
        }
        *(bf16x8*)(w1f + (size_t)g * 8) = v;
    } else if (t < 12288) {               // op_w2: [256][256] -> [kt<8][nt<16][64][8]
        int g = t - 4096, lane = g & 63, nt = (g >> 6) & 15, kt = g >> 10;
        int n = nt * 16 + (lane & 15);
        int k0 = kt * 32 + (lane >> 4) * 8;
        const float* src = op_w2 + (size_t)n * 256 + k0;
        bf16x8 v;
        for (int j = 0; j < 8; ++j) v[j] = (bf16_t)src[j];
        *(bf16x8*)(w2f + (size_t)g * 8) = v;
    } else if (t < 14336) {               // nm_w1: [128][128] -> [kt<4][nt<8][64][8], BN-scaled
        int g = t - 12288, lane = g & 63, nt = (g >> 6) & 7, kt = g >> 9;
        int n = nt * 16 + (lane & 15);
        int k0 = kt * 32 + (lane >> 4) * 8;
        const float* src = nm_w1 + (size_t)n * 128 + k0;
        bf16x8 v;
        for (int j = 0; j < 8; ++j) {
            int i = k0 + j;
            float s = nm_g[i] * rsqrtf(nm_v[i] + EPS);
            v[j] = (bf16_t)(src[j] * s);
        }
        *(bf16x8*)(nw1f + (size_t)g * 8) = v;
    } else if (t < 16384) {               // nm_w2: [128][128] -> [kt<4][nt<8][64][8]
        int g = t - 14336, lane = g & 63, nt = (g >> 6) & 7, kt = g >> 9;
        int n = nt * 16 + (lane & 15);
        int k0 = kt * 32 + (lane >> 4) * 8;
        const float* src = nm_w2 + (size_t)n * 128 + k0;
        bf16x8 v;
        for (int j = 0; j < 8; ++j) v[j] = (bf16_t)src[j];
        *(bf16x8*)(nw2f + (size_t)g * 8) = v;
    } else if (t < 16640) {               // b1p[o] = op_b1[o] + op_w1[o,:] @ shift
        int o = t - 16384;
        float acc = op_b1[o];
        const float* wrow = op_w1 + (size_t)o * 128;
        for (int i = 0; i < 128; ++i) {
            float s  = op_g[i] * rsqrtf(op_v[i] + EPS);
            float sh = op_b[i] - op_m[i] * s;
            acc += wrow[i] * sh;
        }
        b1p[o] = acc;
    } else if (t < 16768) {               // b1n[o] = nm_b1[o] + nm_w1[o,:] @ shift
        int o = t - 16640;
        float acc = nm_b1[o];
        const float* wrow = nm_w1 + (size_t)o * 128;
        for (int i = 0; i < 128; ++i) {
            float s  = nm_g[i] * rsqrtf(nm_v[i] + EPS);
            float sh = nm_b[i] - nm_m[i] * s;
            acc += wrow[i] * sh;
        }
        b1n[o] = acc;
    }
}

// ---------------------------------------------------------------------------
// Kernel 1: Linear(128->256,BN-folded) + ReLU + Linear(256->256) -> y (bf16)
// 64 tokens / block, 4 waves. GEMM1 computes with SWAPPED operands
// (mfma(W_frag, X_frag)) so each lane holds 4 consecutive out-channels for
// one token -> Hf write is a single ds_write_b64 per (nt,m).
// Ax (16 KB) is aliased into Hf (32 KB): total LDS 32 KB.
// NOTE: plain __launch_bounds__(256) — a (256,4) hint clamped VGPR to 64 and
// spilled the a1[16] fragment array to scratch (+1.26 GB HBM traffic, 2x dur).
// Also fuses the CSR count pass (128 tix entries / block).
// ---------------------------------------------------------------------------
__global__ __launch_bounds__(256) void mlp1_y(
    const float* __restrict__ x,
    const int* __restrict__ tix, int* __restrict__ cnt,
    const bf16_t* __restrict__ w1f, const bf16_t* __restrict__ w2f,
    const float* __restrict__ b1, const float* __restrict__ b2,
    bf16_t* __restrict__ y, int T, int T2)
{
    __shared__ __align__(16) bf16_t S[4 * 8 * 64 * 8];   // 32 KB; Ax(16K) aliased under Hf(32K)
    const int tid  = threadIdx.x;
    const int base = blockIdx.x * 64;

    // ---- fused CSR count: 128 entries per block ----
    if (tid < 128) {
        int e = blockIdx.x * 128 + tid;
        if (e < T2) atomicAdd(&cnt[tix[e]], 1);
    }

    // ---- stage X tile (BN already folded into weights) into B-frag layout ----
    {
        const int rr = tid >> 4;      // 0..15
        const int kg = tid & 15;      // 8-col group
        const int c0 = kg * 8;
        for (int p = 0; p < 4; ++p) {
            int r   = p * 16 + rr;
            int tok = base + r;
            float f[8];
            if (tok < T) {
                const float4* xp = (const float4*)(x + (size_t)tok * 128 + c0);
                float4 u = xp[0], w = xp[1];
                f[0] = u.x; f[1] = u.y; f[2] = u.z; f[3] = u.w;
                f[4] = w.x; f[5] = w.y; f[6] = w.z; f[7] = w.w;
            } else {
                for (int j = 0; j < 8; ++j) f[j] = 0.f;
            }
            bf16x8 v;
            for (int j = 0; j < 8; ++j) v[j] = (bf16_t)f[j];
            int flat = ((p * 4 + (kg >> 2)) * 64 + (kg & 3) * 16 + rr) * 8;
            *(bf16x8*)(S + flat) = v;
        }
    }
    __syncthreads();

    const int w     = tid >> 6;       // wave id = nt residue
    const int l     = tid & 63;
    const int colL  = l & 15;
    const int quadw = l >> 4;

    // ---- pull entire X tile into registers, then free the Ax region ----
    bf16x8 a1[16];                    // [m][kt]
    for (int m = 0; m < 4; ++m)
        for (int kt = 0; kt < 4; ++kt)
            a1[m * 4 + kt] = *(const bf16x8*)(S + ((m * 4 + kt) * 64 + l) * 8);
    __syncthreads();                  // all Ax reads done before Hf overwrites

    // ---- GEMM1 (swapped): C rows = channels, cols = tokens ----
    for (int nt_l = 0; nt_l < 4; ++nt_l) {
        const int nt = nt_l * 4 + w;
        f32x4 acc[4];
        for (int m = 0; m < 4; ++m) acc[m] = (f32x4){0.f, 0.f, 0.f, 0.f};
        for (int kt = 0; kt < 4; ++kt) {
            bf16x8 b = *(const bf16x8*)(w1f + (size_t)((kt * 16 + nt) * 64 + l) * 8);
            for (int m = 0; m < 4; ++m)
                acc[m] = __builtin_amdgcn_mfma_f32_16x16x32_bf16(b, a1[m * 4 + kt], acc[m], 0, 0, 0);
        }
        f32x4 bv = *(const f32x4*)(b1 + nt * 16 + 4 * quadw);
        const int kt2 = nt >> 1;
        const int lp  = ((2 * nt + (quadw >> 1)) & 3) * 16 + colL;
        const int jb  = 4 * (quadw & 1);
        for (int m = 0; m < 4; ++m) {
            bf16x4 hv;
            for (int reg = 0; reg < 4; ++reg) {
                float h = acc[m][reg] + bv[reg];
                hv[reg] = (bf16_t)(h > 0.f ? h : 0.f);
            }
            *(bf16x4*)(S + ((m * 8 + kt2) * 64 + lp) * 8 + jb) = hv;
        }
    }
    __syncthreads();

    // ---- GEMM2 (unswapped): Y = H * W2^T + b2; wave w does nt%4==w ----
    for (int mp = 0; mp < 2; ++mp) {
        bf16x8 a2[16];                 // [mm<2][kt<8]
        for (int mm = 0; mm < 2; ++mm)
            for (int kt = 0; kt < 8; ++kt)
                a2[mm * 8 + kt] = *(const bf16x8*)(S + (((2 * mp + mm) * 8 + kt) * 64 + l) * 8);
        for (int nt_l = 0; nt_l < 4; ++nt_l) {
            const int nt = nt_l * 4 + w;
            f32x4 acc0 = {0.f, 0.f, 0.f, 0.f};
            f32x4 acc1 = {0.f, 0.f, 0.f, 0.f};
            for (int kt = 0; kt < 8; ++kt) {
                bf16x8 b = *(const bf16x8*)(w2f + (size_t)((kt * 16 + nt) * 64 + l) * 8);
                acc0 = __builtin_amdgcn_mfma_f32_16x16x32_bf16(a2[kt],     b, acc0, 0, 0, 0);
                acc1 = __builtin_amdgcn_mfma_f32_16x16x32_bf16(a2[8 + kt], b, acc1, 0, 0, 0);
            }
            float bb = b2[nt * 16 + colL];
            int c = nt * 16 + colL;
            for (int reg = 0; reg < 4; ++reg) {
                int r0 = base + (2 * mp) * 16 + quadw * 4 + reg;
                int r1 = base + (2 * mp + 1) * 16 + quadw * 4 + reg;
                if (r0 < T) y[(size_t)r0 * 256 + c] = (bf16_t)(acc0[reg] + bb);
                if (r1 < T) y[(size_t)r1 * 256 + c] = (bf16_t)(acc1[reg] + bb);
            }
        }
    }
}

// ---------------------------------------------------------------------------
// CSR build: scan (3 kernels) -> fill   (count is fused into mlp1_y)
// ---------------------------------------------------------------------------
__global__ __launch_bounds__(256) void scan1(
    const int* __restrict__ cnt, int* __restrict__ bsum, int N)
{
    __shared__ int lds[256];
    int t = threadIdx.x;
    int i0 = blockIdx.x * 1024 + t * 4;
    int s = 0;
    for (int j = 0; j < 4; ++j) { int i = i0 + j; s += (i < N) ? cnt[i] : 0; }
    lds[t] = s; __syncthreads();
    for (int off = 1; off < 256; off <<= 1) {
        int v = (t >= off) ? lds[t - off] : 0;
        __syncthreads(); lds[t] += v; __syncthreads();
    }
    if (t == 255) bsum[blockIdx.x] = lds[255];
}

__global__ __launch_bounds__(256) void scan2(
    const int* __restrict__ bsum, int* __restrict__ bpref, int nb)
{
    __shared__ int lds[256];
    int t = threadIdx.x;
    int s = (t < nb) ? bsum[t] : 0;
    lds[t] = s; __syncthreads();
    for (int off = 1; off < 256; off <<= 1) {
        int v = (t >= off) ? lds[t - off] : 0;
        __syncthreads(); lds[t] += v; __syncthreads();
    }
    if (t < nb) bpref[t] = lds[t] - s;   // exclusive
}

__global__ __launch_bounds__(256) void scan3(
    const int* __restrict__ cnt, const int* __restrict__ bpref,
    int* __restrict__ offs, int* __restrict__ run, int N)
{
    __shared__ int lds[256];
    int t = threadIdx.x;
    int i0 = blockIdx.x * 1024 + t * 4;
    int c[4]; int s = 0;
    for (int j = 0; j < 4; ++j) { int i = i0 + j; c[j] = (i < N) ? cnt[i] : 0; s += c[j]; }
    lds[t] = s; __syncthreads();
    for (int off = 1; off < 256; off <<= 1) {
        int v = (t >= off) ? lds[t - off] : 0;
        __syncthreads(); lds[t] += v; __syncthreads();
    }
    int p = lds[t] - s + bpref[blockIdx.x];
    for (int j = 0; j < 4; ++j) {
        int i = i0 + j;
        if (i < N) { offs[i] = p; run[i] = p; }
        p += c[j];
    }
}

__global__ __launch_bounds__(256) void fill_kernel(
    const int* __restrict__ tix, int* __restrict__ run,
    int* __restrict__ entries, int T2, int T)
{
    int i = blockIdx.x * 256 + threadIdx.x;
    if (i < T2) {
        int n = tix[i];
        int s = (i >= T) ? 1 : 0;
        int t = s ? (i - T) : i;
        int pos = atomicAdd(&run[n], 1);
        entries[pos] = (t << 1) | s;   // y offset of entry = ent*128
    }
}

// ---------------------------------------------------------------------------
// Kernel 2: gather (segment-sum of y) + node MLP fused, writes d_out.
// 64 nodes / block. LDS is fully wave-private (each wave owns one 4 KB
// quarter for staging, GEMM1 H, and GEMM2 input) -> single 16 KB aliased
// buffer, NO barriers: waves with unequal gather loads never sync.
// GEMM1 swapped-operand like mlp1_y -> vector b64 H writes.
// Live register set is small (a1f[4]/a2f[4]) so the (256,4) cap is safe here.
// ---------------------------------------------------------------------------
__global__ __launch_bounds__(256, 4) void gather_mlp2(
    const bf16_t* __restrict__ y,
    const int* __restrict__ offs, const int* __restrict__ cnt,
    const int* __restrict__ entries,
    const bf16_t* __restrict__ w1f, const bf16_t* __restrict__ w2f,
    const float* __restrict__ b1, const float* __restrict__ b2,
    float* __restrict__ out, int N)
{
    __shared__ __align__(16) bf16_t S[4 * 4 * 64 * 8];   // 16 KB, wave-private quarters
    const int tid  = threadIdx.x;
    const int base = blockIdx.x * 64;
    const int w    = tid >> 6;
    const int l    = tid & 63;

    // ---- gather (BN folded into weights), write B-frags into own quarter ----
    {
        const int half = l >> 5;          // which of 2 concurrent nodes
        const int cl   = l & 31;
        const int c0   = cl * 4;          // 4 columns per lane
        for (int ii = 0; ii < 8; ++ii) {
            int r = w * 16 + ii * 2 + half;
            int n = base + r;
            float a[4] = {0.f, 0.f, 0.f, 0.f};
            if (n < N) {
                int e0 = offs[n], c = cnt[n];
                int e = 0;
                for (; e + 4 <= c; e += 4) {
                    int t0 = entries[e0 + e];
                    int t1 = entries[e0 + e + 1];
                    int t2 = entries[e0 + e + 2];
                    int t3 = entries[e0 + e + 3];
                    bf16x4 v0 = *(const bf16x4*)(y + (size_t)t0 * 128 + c0);
                    bf16x4 v1 = *(const bf16x4*)(y + (size_t)t1 * 128 + c0);
                    bf16x4 v2 = *(const bf16x4*)(y + (size_t)t2 * 128 + c0);
                    bf16x4 v3 = *(const bf16x4*)(y + (size_t)t3 * 128 + c0);
                    for (int j = 0; j < 4; ++j)
                        a[j] += ((float)v0[j] + (float)v1[j]) + ((float)v2[j] + (float)v3[j]);
                }
                for (; e < c; ++e) {
                    int t0 = entries[e0 + e];
                    bf16x4 v0 = *(const bf16x4*)(y + (size_t)t0 * 128 + c0);
                    for (int j = 0; j < 4; ++j) a[j] += (float)v0[j];
                }
            }
            bf16x4 pv;
            for (int j = 0; j < 4; ++j) pv[j] = (bf16_t)a[j];
            int idx = ((w * 4 + (c0 >> 5)) * 64 + ((c0 >> 3) & 3) * 16 + (r & 15)) * 8 + (c0 & 7);
            *(bf16x4*)(S + idx) = pv;
        }
    }
    // no barrier: all LDS traffic below stays inside this wave's quarter

    const int mt    = w;
    const int colL  = l & 15;
    const int quadw = l >> 4;

    bf16x8 a1f[4];
    for (int kt = 0; kt < 4; ++kt)
        a1f[kt] = *(const bf16x8*)(S + ((mt * 4 + kt) * 64 + l) * 8);

    // ---- GEMM1 (swapped): lane holds 4 consecutive channels, 1 node ----
    for (int nt = 0; nt < 8; ++nt) {
        f32x4 acc = {0.f, 0.f, 0.f, 0.f};
        for (int kt = 0; kt < 4; ++kt) {
            bf16x8 b = *(const bf16x8*)(w1f + (size_t)((kt * 8 + nt) * 64 + l) * 8);
            acc = __builtin_amdgcn_mfma_f32_16x16x32_bf16(b, a1f[kt], acc, 0, 0, 0);
        }
        f32x4 bv = *(const f32x4*)(b1 + nt * 16 + 4 * quadw);
        const int kt2 = nt >> 1;
        const int lp  = ((2 * nt + (quadw >> 1)) & 3) * 16 + colL;
        const int jb  = 4 * (quadw & 1);
        bf16x4 hv;
        for (int reg = 0; reg < 4; ++reg) {
            float h = acc[reg] + bv[reg];
            hv[reg] = (bf16_t)(h > 0.f ? h : 0.f);
        }
        *(bf16x4*)(S + ((mt * 4 + kt2) * 64 + lp) * 8 + jb) = hv;
    }

    bf16x8 a2f[4];
    for (int kt = 0; kt < 4; ++kt)
        a2f[kt] = *(const bf16x8*)(S + ((mt * 4 + kt) * 64 + l) * 8);
    for (int nt = 0; nt < 8; ++nt) {
        f32x4 acc = {0.f, 0.f, 0.f, 0.f};
        for (int kt = 0; kt < 4; ++kt) {
            bf16x8 b = *(const bf16x8*)(w2f + (size_t)((kt * 8 + nt) * 64 + l) * 8);
            acc = __builtin_amdgcn_mfma_f32_16x16x32_bf16(a2f[kt], b, acc, 0, 0, 0);
        }
        float bb = b2[nt * 16 + colL];
        int c = nt * 16 + colL;
        for (int reg = 0; reg < 4; ++reg) {
            int row = base + mt * 16 + quadw * 4 + reg;
            if (row < N) out[(size_t)row * 128 + c] = acc[reg] + bb;
        }
    }
}

// ---------------------------------------------------------------------------
extern "C" void kernel_launch(void* const* d_in, const int* in_sizes, int n_in,
                              void* d_out, int out_size, void* d_ws, size_t ws_size,
                              hipStream_t stream)
{
    const float* x     = (const float*)d_in[0];
    const int*   tix   = (const int*)d_in[3];
    const float* op_g  = (const float*)d_in[4];
    const float* op_b  = (const float*)d_in[5];
    const float* op_m  = (const float*)d_in[6];
    const float* op_v  = (const float*)d_in[7];
    const float* op_w1 = (const float*)d_in[8];
    const float* op_b1 = (const float*)d_in[9];
    const float* op_w2 = (const float*)d_in[10];
    const float* op_b2 = (const float*)d_in[11];
    const float* nm_g  = (const float*)d_in[12];
    const float* nm_b  = (const float*)d_in[13];
    const float* nm_m  = (const float*)d_in[14];
    const float* nm_v  = (const float*)d_in[15];
    const float* nm_w1 = (const float*)d_in[16];
    const float* nm_b1 = (const float*)d_in[17];
    const float* nm_w2 = (const float*)d_in[18];
    const float* nm_b2 = (const float*)d_in[19];

    const int T  = in_sizes[0] / 128;
    const int N  = in_sizes[2];
    const int T2 = 2 * T;

    char* w = (char*)d_ws;
    size_t off = 0;
    bf16_t* y = (bf16_t*)w;              off += (size_t)T * 256 * 2;
    off = (off + 255) & ~(size_t)255;
    bf16_t* w1f  = (bf16_t*)(w + off);   off += (size_t)4096 * 8 * 2;
    bf16_t* w2f  = (bf16_t*)(w + off);   off += (size_t)8192 * 8 * 2;
    bf16_t* nw1f = (bf16_t*)(w + off);   off += (size_t)2048 * 8 * 2;
    bf16_t* nw2f = (bf16_t*)(w + off);   off += (size_t)2048 * 8 * 2;
    float* b1p   = (float*)(w + off);    off += 256 * 4;
    float* b1n   = (float*)(w + off);    off += 128 * 4;
    int* cnt     = (int*)(w + off);      off += (size_t)N * 4;
    int* offs    = (int*)(w + off);      off += (size_t)N * 4;
    int* run     = (int*)(w + off);      off += (size_t)N * 4;
    int* bsum    = (int*)(w + off);      off += 1024 * 4;
    int* bpref   = (int*)(w + off);      off += 1024 * 4;
    int* entries = (int*)(w + off);      off += (size_t)T2 * 4;

    const int nb = (N + 1023) / 1024;    // scan blocks (must be <= 256)

    hipMemsetAsync(cnt, 0, (size_t)N * 4, stream);
    prep_kernel<<<66, 256, 0, stream>>>(op_w1, op_w2, nm_w1, nm_w2,
                                        op_g, op_b, op_m, op_v,
                                        nm_g, nm_b, nm_m, nm_v,
                                        op_b1, nm_b1,
                                        w1f, w2f, nw1f, nw2f, b1p, b1n);
    mlp1_y<<<(T + 63) / 64, 256, 0, stream>>>(x, tix, cnt, w1f, w2f,
                                              b1p, op_b2, y, T, T2);
    scan1<<<nb, 256, 0, stream>>>(cnt, bsum, N);
    scan2<<<1, 256, 0, stream>>>(bsum, bpref, nb);
    scan3<<<nb, 256, 0, stream>>>(cnt, bpref, offs, run, N);
    fill_kernel<<<(T2 + 255) / 256, 256, 0, stream>>>(tix, run, entries, T2, T);
    gather_mlp2<<<(N + 63) / 64, 256, 0, stream>>>(y, offs, cnt, entries,
                                                   nw1f, nw2f,
                                                   b1n, nm_b2, (float*)d_out, N);
}